// Round 1
// baseline (2726.640 us; speedup 1.0000x reference)
//
#include <hip/hip_runtime.h>
#include <hip/hip_bf16.h>

#define T_ 2048
#define B_ 1024
#define H_ 256
#define I_ 8
#define A_ 8
#define DT_ 0.1f
#define EPS_ 1e-5f
#define LSTR 296  // bf16 elems per h_lds row: 288 cols + 8 pad (148 dwords -> 2-way banks max)

typedef __attribute__((ext_vector_type(8))) short bf16x8;
typedef __attribute__((ext_vector_type(4))) float f32x4;

__device__ __forceinline__ short f2bf(float f) {
    unsigned u = __builtin_bit_cast(unsigned, f);
    u += 0x7fffu + ((u >> 16) & 1u);   // round-to-nearest-even
    return (short)(u >> 16);
}

__launch_bounds__(512, 2)
__global__ void liquid_kernel(const float* __restrict__ x,
                              const float* __restrict__ W_in,
                              const float* __restrict__ b_in,
                              const float* __restrict__ tau_param,
                              const float* __restrict__ W_rec,
                              const float* __restrict__ g1,
                              const float* __restrict__ beta1,
                              const float* __restrict__ g2,
                              const float* __restrict__ beta2,
                              const float* __restrict__ head_w,
                              const float* __restrict__ head_b,
                              float* __restrict__ out) {
    __shared__ short  h_lds[16 * LSTR];     // h_t (bf16) cols 0..255, x_t cols 256..263, zeros 264..287
    __shared__ float2 red[8][16];           // per-wave LN partials (sum, sumsq) per row
    __shared__ float  hw[H_ * A_];          // head_w staging (epilogue)
    __shared__ float  outp[8][16][A_];      // per-wave head partials (epilogue)

    const int tid  = threadIdx.x;
    const int w    = tid >> 6;    // wave 0..7 -> owns s-cols [w*32, w*32+32)
    const int lane = tid & 63;
    const int quad = lane >> 4;
    const int l15  = lane & 15;   // batch-row within block (B-frag n / C col)
    const int r0   = blockIdx.x * 16;

    // ---- zero h LDS (h0 = 0, k-pad = 0) ----
    for (int i = tid; i < 16 * LSTR; i += 512) h_lds[i] = 0;

    // ---- static per-lane params for owned s-cols: c = w*32 + mt*16 + quad*4 + r ----
    float p_bin[8], p_g1[8], p_b1[8], p_tinv[8];
    int   p_c[8];
#pragma unroll
    for (int mt = 0; mt < 2; ++mt)
#pragma unroll
        for (int r = 0; r < 4; ++r) {
            int c = w * 32 + mt * 16 + quad * 4 + r;
            int s = mt * 4 + r;
            p_c[s]   = c;
            p_bin[s] = b_in[c];
            p_g1[s]  = g1[c];
            p_b1[s]  = beta1[c];
            float tp = tau_param[c];
            float sp = (tp > 20.f) ? tp : log1pf(expf(tp));  // softplus
            p_tinv[s] = 1.0f / sp;
        }

    // ---- A fragments: A[m=l15][k=quad*8+j] = W_ext[kbase+k][cA], resident in VGPRs ----
    // W_ext rows: 0..255 = W_rec, 256..263 = W_in, 264..287 = 0
    bf16x8 afrag[2][9];
#pragma unroll
    for (int mt = 0; mt < 2; ++mt) {
        int cA = w * 32 + mt * 16 + l15;
#pragma unroll
        for (int ks = 0; ks < 9; ++ks) {
            bf16x8 f;
#pragma unroll
            for (int j = 0; j < 8; ++j) {
                int kg = ks * 32 + quad * 8 + j;
                float v;
                if (kg < 256)      v = W_rec[kg * H_ + cA];
                else if (kg < 264) v = W_in[(kg - 256) * H_ + cA];
                else               v = 0.f;
                f[j] = f2bf(v);
            }
            afrag[mt][ks] = f;
        }
    }

    // ---- x(t=0) into LDS ----
    const int xr = tid >> 3, xi = tid & 7;
    __syncthreads();  // zero-fill done before targeted x write
    if (tid < 128) {
        float xv = x[((size_t)(r0 + xr) * T_ + 0) * I_ + xi];
        h_lds[xr * LSTR + 256 + xi] = f2bf(xv);
    }

    float hreg[8];
#pragma unroll
    for (int s = 0; s < 8; ++s) hreg[s] = 0.f;

    const short* hrow = &h_lds[l15 * LSTR + quad * 8];

    for (int t = 0; t < T_; ++t) {
        __syncthreads();  // h_t and x_t visible

        // prefetch x(t+1) into registers (latency hidden over the whole step)
        float xnext = 0.f;
        if (tid < 128) {
            int tn = (t + 1 < T_) ? (t + 1) : t;
            xnext = x[((size_t)(r0 + xr) * T_ + tn) * I_ + xi];
        }

        // ---- GEMM: s[row=l15][c] = b_in[c] + x_t@W_in + h_t@W_rec ----
        f32x4 acc0, acc1;
#pragma unroll
        for (int r = 0; r < 4; ++r) { acc0[r] = p_bin[r]; acc1[r] = p_bin[4 + r]; }
#pragma unroll
        for (int ks = 0; ks < 9; ++ks) {
            bf16x8 bfr = *reinterpret_cast<const bf16x8*>(hrow + ks * 32);
            acc0 = __builtin_amdgcn_mfma_f32_16x16x32_bf16(afrag[0][ks], bfr, acc0, 0, 0, 0);
            acc1 = __builtin_amdgcn_mfma_f32_16x16x32_bf16(afrag[1][ks], bfr, acc1, 0, 0, 0);
        }

        // ---- LayerNorm stats over the 256 s-cols of row l15 ----
        float S = 0.f, SQ = 0.f;
#pragma unroll
        for (int r = 0; r < 4; ++r) {
            S  += acc0[r] + acc1[r];
            SQ += acc0[r] * acc0[r] + acc1[r] * acc1[r];
        }
        S += __shfl_xor(S, 16, 64);  SQ += __shfl_xor(SQ, 16, 64);
        S += __shfl_xor(S, 32, 64);  SQ += __shfl_xor(SQ, 32, 64);
        if (quad == 0) red[w][l15] = make_float2(S, SQ);
        __syncthreads();
        float St = 0.f, SQt = 0.f;
#pragma unroll
        for (int ww = 0; ww < 8; ++ww) { float2 rp = red[ww][l15]; St += rp.x; SQt += rp.y; }
        const float mu   = St * (1.f / 256.f);
        float var        = SQt * (1.f / 256.f) - mu * mu;
        const float rstd = __builtin_amdgcn_rsqf(var + EPS_);

        // ---- f = tanh(LN*g1+b1); h update; pack new h to LDS ----
#pragma unroll
        for (int s = 0; s < 8; ++s) {
            float v = (s < 4) ? acc0[s & 3] : acc1[s & 3];
            float z = (v - mu) * rstd * p_g1[s] + p_b1[s];
            float e = exp2f(z * 2.885390082f);                    // e^(2z)
            float f = 1.f - 2.f * __builtin_amdgcn_rcpf(e + 1.f); // tanh(z)
            float h = hreg[s];
            h = h + (f - h * p_tinv[s]) * DT_;
            h = fminf(10.f, fmaxf(-10.f, h));
            hreg[s] = h;
        }
#pragma unroll
        for (int mt = 0; mt < 2; ++mt) {
            short4 pk;
            pk.x = f2bf(hreg[mt * 4 + 0]);
            pk.y = f2bf(hreg[mt * 4 + 1]);
            pk.z = f2bf(hreg[mt * 4 + 2]);
            pk.w = f2bf(hreg[mt * 4 + 3]);
            *reinterpret_cast<short4*>(&h_lds[l15 * LSTR + w * 32 + mt * 16 + quad * 4]) = pk;
        }
        if (tid < 128) h_lds[xr * LSTR + 256 + xi] = f2bf(xnext);
    }

    // ---- epilogue: out = LN(h_T; g2,b2) @ head_w + head_b ----
    for (int i = tid; i < H_ * A_; i += 512) hw[i] = head_w[i];
    __syncthreads();  // also protects red reuse across waves

    float S2 = 0.f, SQ2 = 0.f;
#pragma unroll
    for (int s = 0; s < 8; ++s) { S2 += hreg[s]; SQ2 += hreg[s] * hreg[s]; }
    S2 += __shfl_xor(S2, 16, 64);  SQ2 += __shfl_xor(SQ2, 16, 64);
    S2 += __shfl_xor(S2, 32, 64);  SQ2 += __shfl_xor(SQ2, 32, 64);
    if (quad == 0) red[w][l15] = make_float2(S2, SQ2);
    __syncthreads();
    float St = 0.f, SQt = 0.f;
#pragma unroll
    for (int ww = 0; ww < 8; ++ww) { float2 rp = red[ww][l15]; St += rp.x; SQt += rp.y; }
    const float mu   = St * (1.f / 256.f);
    float var        = SQt * (1.f / 256.f) - mu * mu;
    const float rstd = __builtin_amdgcn_rsqf(var + EPS_);

    float pa[8];
#pragma unroll
    for (int a = 0; a < 8; ++a) pa[a] = 0.f;
#pragma unroll
    for (int s = 0; s < 8; ++s) {
        int c = p_c[s];
        float lnh = (hreg[s] - mu) * rstd * g2[c] + beta2[c];
        float4 w0 = *reinterpret_cast<const float4*>(&hw[c * 8]);
        float4 w1 = *reinterpret_cast<const float4*>(&hw[c * 8 + 4]);
        pa[0] += lnh * w0.x; pa[1] += lnh * w0.y; pa[2] += lnh * w0.z; pa[3] += lnh * w0.w;
        pa[4] += lnh * w1.x; pa[5] += lnh * w1.y; pa[6] += lnh * w1.z; pa[7] += lnh * w1.w;
    }
#pragma unroll
    for (int a = 0; a < 8; ++a) {
        pa[a] += __shfl_xor(pa[a], 16, 64);
        pa[a] += __shfl_xor(pa[a], 32, 64);
    }
    if (quad == 0) {
#pragma unroll
        for (int a = 0; a < 8; ++a) outp[w][l15][a] = pa[a];
    }
    __syncthreads();
    if (tid < 128) {
        int r = tid >> 3, a = tid & 7;
        float s = head_b[a];
#pragma unroll
        for (int ww = 0; ww < 8; ++ww) s += outp[ww][r][a];
        out[(size_t)(r0 + r) * A_ + a] = s;
    }
}

extern "C" void kernel_launch(void* const* d_in, const int* in_sizes, int n_in,
                              void* d_out, int out_size, void* d_ws, size_t ws_size,
                              hipStream_t stream) {
    const float* x         = (const float*)d_in[0];
    const float* W_in      = (const float*)d_in[1];
    const float* b_in      = (const float*)d_in[2];
    const float* tau_param = (const float*)d_in[3];
    const float* W_rec     = (const float*)d_in[4];
    const float* g1        = (const float*)d_in[5];
    const float* beta1     = (const float*)d_in[6];
    const float* g2        = (const float*)d_in[7];
    const float* beta2     = (const float*)d_in[8];
    const float* head_w    = (const float*)d_in[9];
    const float* head_b    = (const float*)d_in[10];
    float* out = (float*)d_out;

    liquid_kernel<<<64, 512, 0, stream>>>(x, W_in, b_in, tau_param, W_rec,
                                          g1, beta1, g2, beta2, head_w, head_b, out);
}

// Round 2
// 2633.214 us; speedup vs baseline: 1.0355x; 1.0355x over previous
//
#include <hip/hip_runtime.h>
#include <hip/hip_bf16.h>

#define T_ 2048
#define B_ 1024
#define H_ 256
#define I_ 8
#define A_ 8
#define DT_ 0.1f
#define EPS_ 1e-5f
#define LSTR 296  // bf16 elems per h_lds row: 288 cols + 8 pad; 2-way bank aliasing only (free)

typedef __attribute__((ext_vector_type(8))) short bf16x8;
typedef __attribute__((ext_vector_type(4))) float f32x4;

#if __has_builtin(__builtin_amdgcn_cvt_pk_bf16_f32)
typedef __attribute__((ext_vector_type(2))) __bf16 bf16x2;
__device__ __forceinline__ int pk2bf(float a, float b) {
    bf16x2 r = __builtin_amdgcn_cvt_pk_bf16_f32(a, b);
    return __builtin_bit_cast(int, r);
}
#else
__device__ __forceinline__ short f2bf1(float f) {
    unsigned u = __builtin_bit_cast(unsigned, f);
    u += 0x7fffu + ((u >> 16) & 1u);   // RNE
    return (short)(u >> 16);
}
__device__ __forceinline__ int pk2bf(float a, float b) {
    return (int)(unsigned short)f2bf1(a) | ((int)f2bf1(b) << 16);
}
#endif

__launch_bounds__(512, 2)
__global__ void liquid_kernel(const float* __restrict__ x,
                              const float* __restrict__ W_in,
                              const float* __restrict__ b_in,
                              const float* __restrict__ tau_param,
                              const float* __restrict__ W_rec,
                              const float* __restrict__ g1,
                              const float* __restrict__ beta1,
                              const float* __restrict__ g2,
                              const float* __restrict__ beta2,
                              const float* __restrict__ head_w,
                              const float* __restrict__ head_b,
                              float* __restrict__ out) {
    __shared__ short  h_lds[16 * LSTR];     // h_t (bf16) cols 0..255, x_t cols 256..263, zeros 264..287
    __shared__ float2 red[8][16];           // per-wave LN partials (sum, sumsq) per row
    __shared__ float  hw[H_ * A_];          // head_w staging (epilogue)
    __shared__ float  outp[8][16][A_];      // per-wave head partials (epilogue)

    const int tid  = threadIdx.x;
    const int w    = tid >> 6;    // wave 0..7 -> owns s-cols [w*32, w*32+32)
    const int lane = tid & 63;
    const int quad = lane >> 4;
    const int l15  = lane & 15;   // batch-row within block (B-frag n / C col)
    const int r0   = blockIdx.x * 16;

    // ---- zero h LDS (h0 = 0, k-pad = 0) ----
    for (int i = tid; i < 16 * LSTR; i += 512) h_lds[i] = 0;

    // ---- static per-lane params for owned s-cols: c = w*32 + mt*16 + quad*4 + r ----
    float p_bin[8], p_g1[8], p_b1[8], p_decay[8];
#pragma unroll
    for (int mt = 0; mt < 2; ++mt)
#pragma unroll
        for (int r = 0; r < 4; ++r) {
            int c = w * 32 + mt * 16 + quad * 4 + r;
            int s = mt * 4 + r;
            p_bin[s] = b_in[c];
            p_g1[s]  = g1[c];
            p_b1[s]  = beta1[c];
            float tp = tau_param[c];
            float sp = (tp > 20.f) ? tp : log1pf(expf(tp));  // softplus
            p_decay[s] = 1.0f - DT_ / sp;
        }

    // ---- A fragments: A[m=l15][k=quad*8+j] = W_ext[kbase+k][cA], resident in VGPRs ----
    // W_ext rows: 0..255 = W_rec, 256..263 = W_in, 264..287 = 0
    bf16x8 afrag[2][9];
#pragma unroll
    for (int mt = 0; mt < 2; ++mt) {
        int cA = w * 32 + mt * 16 + l15;
#pragma unroll
        for (int ks = 0; ks < 9; ++ks) {
            bf16x8 f;
#pragma unroll
            for (int j = 0; j < 8; ++j) {
                int kg = ks * 32 + quad * 8 + j;
                float v;
                if (kg < 256)      v = W_rec[kg * H_ + cA];
                else if (kg < 264) v = W_in[(kg - 256) * H_ + cA];
                else               v = 0.f;
                f[j] = (short)pk2bf(v, v);
            }
            afrag[mt][ks] = f;
        }
    }

    // ---- x loader assignment: lanes 0..15 of EVERY wave load 1 value (uniform skew) ----
    const bool xldr = (l15 == lane);          // lane < 16
    const int  xv   = w * 16 + l15;           // 0..127
    const int  xrow = xv >> 3, xxi = xv & 7;
    const float* xptr = x + (size_t)(r0 + xrow) * T_ * I_ + xxi;

    __syncthreads();  // zero-fill visible before targeted x(0) write
    float xreg = 0.f;
    if (xldr) {
        h_lds[xrow * LSTR + 256 + xxi] = (short)pk2bf(xptr[0], xptr[0]);  // x(t=0)
        xreg = xptr[I_];                                                   // x(t=1)
    }

    float hreg[8];
#pragma unroll
    for (int s = 0; s < 8; ++s) hreg[s] = 0.f;

    const short* hrow = &h_lds[l15 * LSTR + quad * 8];

    for (int t = 0; t < T_; ++t) {
        __syncthreads();  // h_t and x_t visible (barrier #1)

        // prefetch x(t+2): ~2 full steps of latency cover, uniform across waves
        float xnx = 0.f;
        if (xldr) {
            int tn = t + 2; if (tn > T_ - 1) tn = T_ - 1;
            xnx = xptr[(size_t)tn * I_];
        }

        // ---- GEMM: s[row=l15][c] = b_in[c] + x_t@W_in + h_t@W_rec ----
        f32x4 acc0, acc1;
#pragma unroll
        for (int r = 0; r < 4; ++r) { acc0[r] = p_bin[r]; acc1[r] = p_bin[4 + r]; }
#pragma unroll
        for (int ks = 0; ks < 9; ++ks) {
            bf16x8 bfr = *reinterpret_cast<const bf16x8*>(hrow + ks * 32);
            acc0 = __builtin_amdgcn_mfma_f32_16x16x32_bf16(afrag[0][ks], bfr, acc0, 0, 0, 0);
            acc1 = __builtin_amdgcn_mfma_f32_16x16x32_bf16(afrag[1][ks], bfr, acc1, 0, 0, 0);
        }

        // ---- LN partial (this wave's 8 cols of row l15) ----
        float S = 0.f, SQ = 0.f;
#pragma unroll
        for (int r = 0; r < 4; ++r) {
            S += acc0[r];  SQ = fmaf(acc0[r], acc0[r], SQ);
            S += acc1[r];  SQ = fmaf(acc1[r], acc1[r], SQ);
        }
        S += __shfl_xor(S, 16, 64);  SQ += __shfl_xor(SQ, 16, 64);
        S += __shfl_xor(S, 32, 64);  SQ += __shfl_xor(SQ, 32, 64);
        if (quad == 0) red[w][l15] = make_float2(S, SQ);
        __syncthreads();  // barrier #2

        // ---- 2-stage cross-wave reduce: quad q sums partials q and q+4, then shfl ----
        float2 rA = red[quad][l15], rB = red[quad + 4][l15];
        float St = rA.x + rB.x, SQt = rA.y + rB.y;
        St += __shfl_xor(St, 16, 64);  SQt += __shfl_xor(SQt, 16, 64);
        St += __shfl_xor(St, 32, 64);  SQt += __shfl_xor(SQt, 32, 64);
        const float mu   = St * (1.f / 256.f);
        const float var  = fmaf(SQt, 1.f / 256.f, -mu * mu);
        const float rstd = __builtin_amdgcn_rsqf(var + EPS_);
        const float nmr  = -mu * rstd;

        // ---- f = tanh(LN*g1+b1); h = clamp(h*decay + DT*f) ----
#pragma unroll
        for (int s = 0; s < 8; ++s) {
            float v  = (s < 4) ? acc0[s] : acc1[s - 4];
            float tt = fmaf(v, rstd, nmr);
            float z  = fmaf(tt, p_g1[s], p_b1[s]);
            float e  = exp2f(z * 2.885390082f);                 // e^(2z)
            float rc = __builtin_amdgcn_rcpf(e + 1.f);
            float fd = fmaf(rc, -2.f * DT_, DT_);               // DT*tanh(z)
            float h  = fmaf(hreg[s], p_decay[s], fd);
            hreg[s]  = fminf(10.f, fmaxf(-10.f, h));
        }
        // pack new h (bf16) to LDS: 4 cvt_pk + 2 ds_write_b64
        int2 pk0 = make_int2(pk2bf(hreg[0], hreg[1]), pk2bf(hreg[2], hreg[3]));
        int2 pk1 = make_int2(pk2bf(hreg[4], hreg[5]), pk2bf(hreg[6], hreg[7]));
        *reinterpret_cast<int2*>(&h_lds[l15 * LSTR + w * 32 + quad * 4])      = pk0;
        *reinterpret_cast<int2*>(&h_lds[l15 * LSTR + w * 32 + 16 + quad * 4]) = pk1;
        if (xldr) {
            h_lds[xrow * LSTR + 256 + xxi] = (short)pk2bf(xreg, xreg);  // publish x_{t+1}
            xreg = xnx;
        }
    }

    // ---- epilogue: out = LN(h_T; g2,b2) @ head_w + head_b ----
    for (int i = tid; i < H_ * A_; i += 512) hw[i] = head_w[i];
    __syncthreads();  // hw staged; also protects red reuse

    float S2 = 0.f, SQ2 = 0.f;
#pragma unroll
    for (int s = 0; s < 8; ++s) { S2 += hreg[s]; SQ2 = fmaf(hreg[s], hreg[s], SQ2); }
    S2 += __shfl_xor(S2, 16, 64);  SQ2 += __shfl_xor(SQ2, 16, 64);
    S2 += __shfl_xor(S2, 32, 64);  SQ2 += __shfl_xor(SQ2, 32, 64);
    if (quad == 0) red[w][l15] = make_float2(S2, SQ2);
    __syncthreads();
    float2 rA = red[quad][l15], rB = red[quad + 4][l15];
    float St = rA.x + rB.x, SQt = rA.y + rB.y;
    St += __shfl_xor(St, 16, 64);  SQt += __shfl_xor(SQt, 16, 64);
    St += __shfl_xor(St, 32, 64);  SQt += __shfl_xor(SQt, 32, 64);
    const float mu   = St * (1.f / 256.f);
    const float var  = fmaf(SQt, 1.f / 256.f, -mu * mu);
    const float rstd = __builtin_amdgcn_rsqf(var + EPS_);

    float pa[8];
#pragma unroll
    for (int a = 0; a < 8; ++a) pa[a] = 0.f;
#pragma unroll
    for (int s = 0; s < 8; ++s) {
        int c = w * 32 + (s >> 2) * 16 + quad * 4 + (s & 3);
        float lnh = (hreg[s] - mu) * rstd * g2[c] + beta2[c];
        float4 w0 = *reinterpret_cast<const float4*>(&hw[c * 8]);
        float4 w1 = *reinterpret_cast<const float4*>(&hw[c * 8 + 4]);
        pa[0] += lnh * w0.x; pa[1] += lnh * w0.y; pa[2] += lnh * w0.z; pa[3] += lnh * w0.w;
        pa[4] += lnh * w1.x; pa[5] += lnh * w1.y; pa[6] += lnh * w1.z; pa[7] += lnh * w1.w;
    }
#pragma unroll
    for (int a = 0; a < 8; ++a) {
        pa[a] += __shfl_xor(pa[a], 16, 64);
        pa[a] += __shfl_xor(pa[a], 32, 64);
    }
    if (quad == 0) {
#pragma unroll
        for (int a = 0; a < 8; ++a) outp[w][l15][a] = pa[a];
    }
    __syncthreads();
    if (tid < 128) {
        int r = tid >> 3, a = tid & 7;
        float s = head_b[a];
#pragma unroll
        for (int ww = 0; ww < 8; ++ww) s += outp[ww][r][a];
        out[(size_t)(r0 + r) * A_ + a] = s;
    }
}

extern "C" void kernel_launch(void* const* d_in, const int* in_sizes, int n_in,
                              void* d_out, int out_size, void* d_ws, size_t ws_size,
                              hipStream_t stream) {
    const float* x         = (const float*)d_in[0];
    const float* W_in      = (const float*)d_in[1];
    const float* b_in      = (const float*)d_in[2];
    const float* tau_param = (const float*)d_in[3];
    const float* W_rec     = (const float*)d_in[4];
    const float* g1        = (const float*)d_in[5];
    const float* beta1     = (const float*)d_in[6];
    const float* g2        = (const float*)d_in[7];
    const float* beta2     = (const float*)d_in[8];
    const float* head_w    = (const float*)d_in[9];
    const float* head_b    = (const float*)d_in[10];
    float* out = (float*)d_out;

    liquid_kernel<<<64, 512, 0, stream>>>(x, W_in, b_in, tau_param, W_rec,
                                          g1, beta1, g2, beta2, head_w, head_b, out);
}